// Round 1
// baseline (299.362 us; speedup 1.0000x reference)
//
#include <hip/hip_runtime.h>

// Problem constants (from reference):
//   S,T,U,V = 9,9,512,512 ; H,W = 512,512 ; N = 4 ; EPS = 1e-6
// data:      (S,T,U,V,3) float32   d_in[0]
// pixel:     (H,W)       float32   d_in[1]  (unused, shape-only)
// cam_xyz:   (3,)        float32   d_in[2]
// neighbors: (N,2)       int32     d_in[3]
// uv:        (N,H,W,2)   int32     d_in[4]
// out:       flat order = (H*W, 3) row-major, i.e. out[k*3+c]
//            (reference flat-reshapes (HW,3) -> (3,H,W); memory order unchanged)

#define Td 9
#define Ud 512
#define Vd 512
#define HW (512 * 512)
#define EPSF 1e-6f

__global__ __launch_bounds__(256) void interp_kernel(
    const float* __restrict__ data,
    const float* __restrict__ cam,
    const int* __restrict__ neighbors,
    const int* __restrict__ uv,
    float* __restrict__ out)
{
    const int k = blockIdx.x * blockDim.x + threadIdx.x;
    if (k >= HW) return;

    // ---- weights (all threads redundantly; scalar-broadcast loads) ----
    const float cx = cam[0];
    const float cy = cam[1];
    float t[4];
#pragma unroll
    for (int n = 0; n < 4; ++n) {
        // flip: weight slot n comes from neighbor (3-n)'s distance product
        const int ns = neighbors[2 * (3 - n) + 0];
        const int nt = neighbors[2 * (3 - n) + 1];
        const float dx = cx - (float)ns;
        const float dy = cy - (float)nt;
        float v = fabsf(dx * dy);
        t[n] = (v <= EPSF) ? 0.0f : v;
    }
    const float tsum = t[0] + t[1] + t[2] + t[3];

    float acc0 = 0.0f, acc1 = 0.0f, acc2 = 0.0f;
#pragma unroll
    for (int n = 0; n < 4; ++n) {
        float w = t[n] / tsum;
        if (fabsf(w) <= EPSF) w = 0.0f;
        const int ns = neighbors[2 * n + 0];
        const int nt = neighbors[2 * n + 1];
        // coalesced int2 load of (u,v) for this pixel/neighbor
        const int2 uvv = *reinterpret_cast<const int2*>(&uv[((size_t)n * HW + k) * 2]);
        const int off = (((ns * Td + nt) * Ud + uvv.x) * Vd + uvv.y) * 3;
        acc0 += w * data[off + 0];
        acc1 += w * data[off + 1];
        acc2 += w * data[off + 2];
    }

    // contiguous 12B store per thread: out[k*3 + c]
    out[k * 3 + 0] = acc0;
    out[k * 3 + 1] = acc1;
    out[k * 3 + 2] = acc2;
}

extern "C" void kernel_launch(void* const* d_in, const int* in_sizes, int n_in,
                              void* d_out, int out_size, void* d_ws, size_t ws_size,
                              hipStream_t stream)
{
    const float* data      = (const float*)d_in[0];
    // d_in[1] = pixel, unused (shape-only in reference)
    const float* cam       = (const float*)d_in[2];
    const int*   neighbors = (const int*)d_in[3];
    const int*   uv        = (const int*)d_in[4];
    float*       out       = (float*)d_out;

    const int threads = 256;
    const int blocks  = (HW + threads - 1) / threads;
    interp_kernel<<<blocks, threads, 0, stream>>>(data, cam, neighbors, uv, out);
}